// Round 1
// baseline (1409.624 us; speedup 1.0000x reference)
//
#include <hip/hip_runtime.h>

#define N_NODES 100000
#define N_EDGES 800000
#define N_GRAPH 256
#define MP      100096   // 782 * 128, padded M
#define NH      512

typedef __bf16 bf16x4v __attribute__((ext_vector_type(4)));
typedef __bf16 bf16x8v __attribute__((ext_vector_type(8)));
typedef float  f32x4   __attribute__((ext_vector_type(4)));

__device__ __forceinline__ void gload_lds16(const void* g, void* l) {
  __builtin_amdgcn_global_load_lds((const __attribute__((address_space(1))) void*)g,
                                   (__attribute__((address_space(3))) void*)l, 16, 0, 0);
}

// ---------------- cast x (fp32) -> padded bf16 [MP][512] ----------------
__global__ __launch_bounds__(256) void castx_kernel(const float* __restrict__ x,
                                                    __bf16* __restrict__ xb) {
  const size_t i = (size_t)blockIdx.x * 256 + threadIdx.x;   // 8-elem chunk id
  const size_t row = i >> 6;
  const int c = (int)(i & 63) * 8;
  if (row >= MP) return;
  bf16x8v o;
  if (row < N_NODES) {
    const float* p = x + row * 512 + c;
    f32x4 a = *(const f32x4*)p;
    f32x4 b = *(const f32x4*)(p + 4);
    o[0]=(__bf16)a[0]; o[1]=(__bf16)a[1]; o[2]=(__bf16)a[2]; o[3]=(__bf16)a[3];
    o[4]=(__bf16)b[0]; o[5]=(__bf16)b[1]; o[6]=(__bf16)b[2]; o[7]=(__bf16)b[3];
  } else {
    for (int j = 0; j < 8; ++j) o[j] = (__bf16)0.0f;
  }
  *(bf16x8v*)(xb + row * 512 + c) = o;
}

// ---------------- weight transpose: W[K][N] fp32 -> BT[N][K] bf16 ----------------
__global__ __launch_bounds__(256) void transpose_kernel(const float* __restrict__ W,
                                                        __bf16* __restrict__ BT,
                                                        int K, int Nn) {
  __shared__ float tile[32][33];
  const int bx = blockIdx.x;   // n tile
  const int by = blockIdx.y;   // k tile
  const int tx = threadIdx.x & 31;
  const int ty = threadIdx.x >> 5;   // 0..7
  for (int j = 0; j < 4; ++j) {
    int k = by * 32 + ty + j * 8;
    int n = bx * 32 + tx;
    tile[ty + j * 8][tx] = W[(size_t)k * Nn + n];
  }
  __syncthreads();
  for (int j = 0; j < 4; ++j) {
    int n = bx * 32 + ty + j * 8;
    int k = by * 32 + tx;
    BT[(size_t)n * K + k] = (__bf16)tile[tx][ty + j * 8];
  }
}

// ---------------- CSR build ----------------
__global__ __launch_bounds__(256) void degree_kernel(const int* __restrict__ dst,
                                                     int* __restrict__ deg) {
  int e = blockIdx.x * 256 + threadIdx.x;
  if (e < N_EDGES) atomicAdd(&deg[dst[e]], 1);
}

__global__ __launch_bounds__(256) void scan1_kernel(const int* __restrict__ deg,
                                                    int* __restrict__ rs,
                                                    int* __restrict__ bsum, int n) {
  __shared__ int lds[256];
  const int b = blockIdx.x, t = threadIdx.x;
  const int base = b * 1024 + t * 4;
  int v[4];
  for (int j = 0; j < 4; ++j) v[j] = (base + j < n) ? deg[base + j] : 0;
  int tsum = v[0] + v[1] + v[2] + v[3];
  lds[t] = tsum;
  __syncthreads();
  for (int off = 1; off < 256; off <<= 1) {
    int x = 0;
    if (t >= off) x = lds[t - off];
    __syncthreads();
    lds[t] += x;
    __syncthreads();
  }
  int run = lds[t] - tsum;   // exclusive prefix of this thread
  for (int j = 0; j < 4; ++j) {
    if (base + j < n) rs[base + j] = run;
    run += v[j];
  }
  if (t == 255) bsum[b] = lds[255];
}

__global__ void scan2_kernel(int* bsum, int nb) {
  if (threadIdx.x == 0 && blockIdx.x == 0) {
    int run = 0;
    for (int i = 0; i < nb; ++i) { int v = bsum[i]; bsum[i] = run; run += v; }
  }
}

__global__ __launch_bounds__(256) void scan3_kernel(int* __restrict__ rs,
                                                    const int* __restrict__ bsum,
                                                    int* __restrict__ cursor, int n) {
  int i = blockIdx.x * 256 + threadIdx.x;
  if (i < n) {
    int v = rs[i] + bsum[i >> 10];
    rs[i] = v;
    cursor[i] = v;
  } else if (i == n) {
    rs[n] = N_EDGES;
  }
}

__global__ __launch_bounds__(256) void scatter_kernel(const int* __restrict__ src,
                                                      const int* __restrict__ dst,
                                                      int* __restrict__ cursor,
                                                      int* __restrict__ csr) {
  int e = blockIdx.x * 256 + threadIdx.x;
  if (e < N_EDGES) {
    int slot = atomicAdd(&cursor[dst[e]], 1);
    csr[slot] = src[e];
  }
}

// ---------------- aggregate: agg[n] = sum_{e: dst==n} h[src[e]]  (pull, CSR) ----------------
__global__ __launch_bounds__(256) void aggregate_kernel(const __bf16* __restrict__ h,
                                                        const int* __restrict__ rs,
                                                        const int* __restrict__ csr,
                                                        __bf16* __restrict__ agg) {
  const int node = blockIdx.x * 4 + (threadIdx.x >> 6);
  if (node >= N_NODES) return;
  const int lane = threadIdx.x & 63;
  const int s = rs[node], e = rs[node + 1];
  float acc[8] = {0.f,0.f,0.f,0.f,0.f,0.f,0.f,0.f};
  for (int i = s; i < e; ++i) {
    int sn = csr[i];
    bf16x8v v = *(const bf16x8v*)(h + (size_t)sn * 512 + lane * 8);
    for (int j = 0; j < 8; ++j) acc[j] += (float)v[j];
  }
  bf16x8v o;
  for (int j = 0; j < 8; ++j) o[j] = (__bf16)acc[j];
  *(bf16x8v*)(agg + (size_t)node * 512 + lane * 8) = o;
}

// ---------------- GEMM: C[M][512] = relu?( A @ BT^T + bias ), bf16 in/out, fp32 acc ----------
// A split mode: K = 1024, A1 = first 512 cols, A2 = second 512 cols (each [M][512]).
// BT is [512][KTOT] bf16 (pre-transposed weights).
template<int KTOT, bool SPLIT, bool RELU>
__global__ __launch_bounds__(256) void gemm_kernel(const __bf16* __restrict__ A1,
                                                   const __bf16* __restrict__ A2,
                                                   const __bf16* __restrict__ BT,
                                                   const float* __restrict__ bias,
                                                   __bf16* __restrict__ C) {
  __shared__ __bf16 As[128 * 32];
  __shared__ __bf16 Bs[128 * 32];
  const int tid  = threadIdx.x;
  const int wid  = tid >> 6;
  const int lane = tid & 63;
  const int tm = blockIdx.y, tn = blockIdx.x;
  const int wm = wid >> 1, wn = wid & 1;
  const int srow = tid >> 2;          // 0..63
  const int scol = (tid & 3) * 8;     // 0,8,16,24

  f32x4 acc[4][4];
  for (int m = 0; m < 4; ++m)
    for (int n = 0; n < 4; ++n)
      acc[m][n] = f32x4{0.f, 0.f, 0.f, 0.f};

  const int KA = SPLIT ? (KTOT / 2) : KTOT;

  for (int kt = 0; kt < KTOT; kt += 32) {
    const __bf16* Ap = A1;
    int kc = kt;
    if (SPLIT && kt >= KA) { Ap = A2; kc = kt - KA; }
    // stage A tile [128][32] (linear, matches HW lane*16 placement)
    for (int j = 0; j < 2; ++j) {
      const __bf16* g = Ap + (size_t)(tm * 128 + j * 64 + srow) * KA + (kc + scol);
      gload_lds16(g, (char*)As + j * 4096 + wid * 1024);
    }
    // stage B tile [128][32]
    for (int j = 0; j < 2; ++j) {
      const __bf16* g = BT + (size_t)(tn * 128 + j * 64 + srow) * KTOT + (kt + scol);
      gload_lds16(g, (char*)Bs + j * 4096 + wid * 1024);
    }
    __syncthreads();   // compiler drains vmcnt before barrier -> LDS ready

    const int k8 = (lane >> 4) * 8;
    const int rl = lane & 15;
    bf16x8v av[4], bv[4];
    for (int m = 0; m < 4; ++m)
      av[m] = *(const bf16x8v*)(As + (wm * 64 + m * 16 + rl) * 32 + k8);
    for (int n = 0; n < 4; ++n)
      bv[n] = *(const bf16x8v*)(Bs + (wn * 64 + n * 16 + rl) * 32 + k8);
    for (int m = 0; m < 4; ++m)
      for (int n = 0; n < 4; ++n)
        acc[m][n] = __builtin_amdgcn_mfma_f32_16x16x32_bf16(av[m], bv[n], acc[m][n], 0, 0, 0);
    __syncthreads();   // protect LDS before next stage
  }

  // epilogue: bias (+ relu) -> bf16
  const int rl = lane & 15;
  const int rg = (lane >> 4) * 4;
  for (int n = 0; n < 4; ++n) {
    const int col = tn * 128 + wn * 64 + n * 16 + rl;
    const float bv_ = bias[col];
    for (int m = 0; m < 4; ++m) {
      const int rowb = tm * 128 + wm * 64 + m * 16 + rg;
      for (int r = 0; r < 4; ++r) {
        float v = acc[m][n][r] + bv_;
        if (RELU) v = fmaxf(v, 0.f);
        C[(size_t)(rowb + r) * NH + col] = (__bf16)v;
      }
    }
  }
}

// ---------------- memory module: h = softmax(h @ mem^T) @ mem ; also write hc slice --------
__global__ __launch_bounds__(256) void memmod_kernel(__bf16* __restrict__ h,
                                                     const float* __restrict__ mem,
                                                     __bf16* __restrict__ hc, int colofs) {
  __shared__ float sm[8 * 512];
  const int tid = threadIdx.x;
  for (int i = tid; i < 4096; i += 256) sm[i] = mem[i];
  __syncthreads();
  const int node = blockIdx.x * 4 + (tid >> 6);
  if (node >= N_NODES) return;
  const int lane = tid & 63;
  __bf16* hrow = h + (size_t)node * 512;
  float hv[8];
  for (int j = 0; j < 8; ++j) hv[j] = (float)hrow[lane + j * 64];
  float sim[8];
  for (int m = 0; m < 8; ++m) {
    float p = 0.f;
    const float* mr = sm + m * 512 + lane;
    for (int j = 0; j < 8; ++j) p += hv[j] * mr[j * 64];
    for (int off = 32; off; off >>= 1) p += __shfl_xor(p, off, 64);
    sim[m] = p;
  }
  float mx = sim[0];
  for (int m = 1; m < 8; ++m) mx = fmaxf(mx, sim[m]);
  float s = 0.f;
  for (int m = 0; m < 8; ++m) { sim[m] = __expf(sim[m] - mx); s += sim[m]; }
  const float inv = 1.f / s;
  float outv[8] = {0.f,0.f,0.f,0.f,0.f,0.f,0.f,0.f};
  for (int m = 0; m < 8; ++m) {
    float w = sim[m] * inv;
    const float* mr = sm + m * 512 + lane;
    for (int j = 0; j < 8; ++j) outv[j] += w * mr[j * 64];
  }
  __bf16* hcrow = hc + (size_t)node * 1024 + colofs;
  for (int j = 0; j < 8; ++j) {
    __bf16 o = (__bf16)outv[j];
    hrow[lane + j * 64] = o;
    hcrow[lane + j * 64] = o;
  }
}

// ---------------- graph ranges (batch is sorted) ----------------
__global__ __launch_bounds__(256) void ranges_kernel(const int* __restrict__ batch,
                                                     int* __restrict__ gstart) {
  int g = blockIdx.x * 256 + threadIdx.x;
  if (g > N_GRAPH) return;
  if (g == N_GRAPH) { gstart[N_GRAPH] = N_NODES; return; }
  int lo = 0, hi = N_NODES;
  while (lo < hi) {
    int mid = (lo + hi) >> 1;
    if (batch[mid] < g) lo = mid + 1; else hi = mid;
  }
  gstart[g] = lo;
}

// ---------------- pooling: out1 = segment_max, out2 = segment_mean over hc [N][1024] -------
__global__ __launch_bounds__(256) void pool_kernel(const __bf16* __restrict__ hc,
                                                   const int* __restrict__ gstart,
                                                   float* __restrict__ g) {
  const int gr = blockIdx.x;
  const int t = threadIdx.x;   // 256 threads, 4 feats each
  const int s = gstart[gr], e = gstart[gr + 1];
  float mx[4] = {-3.0e38f, -3.0e38f, -3.0e38f, -3.0e38f};
  float sum[4] = {0.f, 0.f, 0.f, 0.f};
  for (int r = s; r < e; ++r) {
    bf16x4v v = *(const bf16x4v*)(hc + (size_t)r * 1024 + t * 4);
    for (int j = 0; j < 4; ++j) {
      float f = (float)v[j];
      mx[j] = fmaxf(mx[j], f);
      sum[j] += f;
    }
  }
  const float invc = 1.f / fmaxf((float)(e - s), 1.f);
  for (int j = 0; j < 4; ++j) {
    int f = t * 4 + j;
    g[(size_t)gr * 2048 + f] = (e > s) ? mx[j] : 0.f;
    g[(size_t)gr * 2048 + 1024 + f] = sum[j] * invc;
  }
}

// ---------------- classifier head: log_softmax(g @ lin_w + lin_b) ----------------
__global__ __launch_bounds__(64) void classify_kernel(const float* __restrict__ g,
                                                      const float* __restrict__ lw,
                                                      const float* __restrict__ lb,
                                                      float* __restrict__ out) {
  const int gr = blockIdx.x;
  const int lane = threadIdx.x;   // 64
  float acc[10];
  for (int c = 0; c < 10; ++c) acc[c] = 0.f;
  const float* grow = g + (size_t)gr * 2048;
  for (int k = lane; k < 2048; k += 64) {
    float gv = grow[k];
    const float* w = lw + (size_t)k * 10;
#pragma unroll
    for (int c = 0; c < 10; ++c) acc[c] += gv * w[c];
  }
  for (int c = 0; c < 10; ++c)
    for (int off = 32; off; off >>= 1) acc[c] += __shfl_xor(acc[c], off, 64);
  if (lane == 0) {
    float lg[10];
    float mx = -3.0e38f;
    for (int c = 0; c < 10; ++c) { lg[c] = acc[c] + lb[c]; mx = fmaxf(mx, lg[c]); }
    float s = 0.f;
    for (int c = 0; c < 10; ++c) s += expf(lg[c] - mx);
    float lse = logf(s);
    for (int c = 0; c < 10; ++c) out[(size_t)gr * 10 + c] = lg[c] - mx - lse;
  }
}

// =======================================================================================
extern "C" void kernel_launch(void* const* d_in, const int* in_sizes, int n_in,
                              void* d_out, int out_size, void* d_ws, size_t ws_size,
                              hipStream_t stream) {
  (void)in_sizes; (void)n_in; (void)out_size; (void)ws_size;
  const float* x      = (const float*)d_in[0];
  const int*   eidx   = (const int*)d_in[1];
  const int*   batch  = (const int*)d_in[2];
  const float* pre_w  = (const float*)d_in[4];
  const float* pre_b  = (const float*)d_in[5];
  const float* w1_0   = (const float*)d_in[6];
  const float* b1_0   = (const float*)d_in[7];
  const float* w2_0   = (const float*)d_in[8];
  const float* b2_0   = (const float*)d_in[9];
  const float* mem_0  = (const float*)d_in[10];
  const float* w1_1   = (const float*)d_in[11];
  const float* b1_1   = (const float*)d_in[12];
  const float* w2_1   = (const float*)d_in[13];
  const float* b2_1   = (const float*)d_in[14];
  const float* mem_1  = (const float*)d_in[15];
  const float* lin_w  = (const float*)d_in[16];
  const float* lin_b  = (const float*)d_in[17];
  float* out = (float*)d_out;

  const int* src = eidx;
  const int* dst = eidx + N_EDGES;

  // ---- workspace carve ----
  char* p = (char*)d_ws;
  auto alloc = [&](size_t bytes) -> char* {
    char* r = p;
    p += (bytes + 255) & ~(size_t)255;
    return r;
  };
  __bf16* xb    = (__bf16*)alloc((size_t)MP * 512 * 2);
  __bf16* hb    = (__bf16*)alloc((size_t)MP * 512 * 2);
  __bf16* aggb  = (__bf16*)alloc((size_t)MP * 512 * 2);
  __bf16* y1b   = (__bf16*)alloc((size_t)MP * 512 * 2);
  __bf16* hcb   = (__bf16*)alloc((size_t)MP * 1024 * 2);
  __bf16* preT  = (__bf16*)alloc((size_t)512 * 512 * 2);
  __bf16* w1T0  = (__bf16*)alloc((size_t)512 * 1024 * 2);
  __bf16* w2T0  = (__bf16*)alloc((size_t)512 * 512 * 2);
  __bf16* w1T1  = (__bf16*)alloc((size_t)512 * 1024 * 2);
  __bf16* w2T1  = (__bf16*)alloc((size_t)512 * 512 * 2);
  int* deg      = (int*)alloc((size_t)N_NODES * 4);
  int* rowstart = (int*)alloc((size_t)(N_NODES + 1) * 4);
  int* cursor   = (int*)alloc((size_t)N_NODES * 4);
  int* bsum     = (int*)alloc(128 * 4);
  int* csr      = (int*)alloc((size_t)N_EDGES * 4);
  int* gstart   = (int*)alloc((size_t)(N_GRAPH + 1) * 4);
  float* gf     = (float*)alloc((size_t)N_GRAPH * 2048 * 4);

  // ---- weight prep (bf16 transposed: BT[n][k]) ----
  transpose_kernel<<<dim3(16, 16), 256, 0, stream>>>(pre_w, preT, 512, 512);
  transpose_kernel<<<dim3(16, 32), 256, 0, stream>>>(w1_0, w1T0, 1024, 512);
  transpose_kernel<<<dim3(16, 16), 256, 0, stream>>>(w2_0, w2T0, 512, 512);
  transpose_kernel<<<dim3(16, 32), 256, 0, stream>>>(w1_1, w1T1, 1024, 512);
  transpose_kernel<<<dim3(16, 16), 256, 0, stream>>>(w2_1, w2T1, 512, 512);

  // ---- input cast ----
  castx_kernel<<<25024, 256, 0, stream>>>(x, xb);

  // ---- CSR build (per call; deterministic work) ----
  hipMemsetAsync(deg, 0, (size_t)N_NODES * 4, stream);
  degree_kernel<<<3125, 256, 0, stream>>>(dst, deg);
  scan1_kernel<<<98, 256, 0, stream>>>(deg, rowstart, bsum, N_NODES);
  scan2_kernel<<<1, 64, 0, stream>>>(bsum, 98);
  scan3_kernel<<<392, 256, 0, stream>>>(rowstart, bsum, cursor, N_NODES);
  scatter_kernel<<<3125, 256, 0, stream>>>(src, dst, cursor, csr);

  const dim3 ggrid(4, 782);

  // ---- pre conv: h = x @ pre_w + pre_b ----
  gemm_kernel<512, false, false><<<ggrid, 256, 0, stream>>>(xb, nullptr, preT, pre_b, hb);

  // ---- layer 0 ----
  aggregate_kernel<<<25000, 256, 0, stream>>>(hb, rowstart, csr, aggb);
  gemm_kernel<1024, true, true><<<ggrid, 256, 0, stream>>>(hb, aggb, w1T0, b1_0, y1b);
  gemm_kernel<512, false, true><<<ggrid, 256, 0, stream>>>(y1b, nullptr, w2T0, b2_0, hb);
  memmod_kernel<<<25000, 256, 0, stream>>>(hb, mem_0, hcb, 0);

  // ---- layer 1 ----
  aggregate_kernel<<<25000, 256, 0, stream>>>(hb, rowstart, csr, aggb);
  gemm_kernel<1024, true, true><<<ggrid, 256, 0, stream>>>(hb, aggb, w1T1, b1_1, y1b);
  gemm_kernel<512, false, true><<<ggrid, 256, 0, stream>>>(y1b, nullptr, w2T1, b2_1, hb);
  memmod_kernel<<<25000, 256, 0, stream>>>(hb, mem_1, hcb, 512);

  // ---- readout ----
  ranges_kernel<<<2, 256, 0, stream>>>(batch, gstart);
  pool_kernel<<<N_GRAPH, 256, 0, stream>>>(hcb, gstart, gf);
  classify_kernel<<<N_GRAPH, 64, 0, stream>>>(gf, lin_w, lin_b, out);
}

// Round 2
// 1309.143 us; speedup vs baseline: 1.0768x; 1.0768x over previous
//
#include <hip/hip_runtime.h>

#define N_NODES 100000
#define N_EDGES 800000
#define N_GRAPH 256
#define MP      100096   // 782 * 128, padded M
#define NH      512

typedef __bf16 bf16x4v __attribute__((ext_vector_type(4)));
typedef __bf16 bf16x8v __attribute__((ext_vector_type(8)));
typedef float  f32x4   __attribute__((ext_vector_type(4)));

__device__ __forceinline__ void gload_lds16(const void* g, void* l) {
  __builtin_amdgcn_global_load_lds((const __attribute__((address_space(1))) void*)g,
                                   (__attribute__((address_space(3))) void*)l, 16, 0, 0);
}

// order-preserving fp32 <-> uint32 encoding for atomicMax
__device__ __forceinline__ unsigned enc_f32(float f) {
  unsigned u = __float_as_uint(f);
  return (u & 0x80000000u) ? ~u : (u | 0x80000000u);
}
__device__ __forceinline__ float dec_f32(unsigned u) {
  return (u & 0x80000000u) ? __uint_as_float(u & 0x7FFFFFFFu) : __uint_as_float(~u);
}

// ---------------- cast x (fp32) -> padded bf16 [MP][512] ----------------
__global__ __launch_bounds__(256) void castx_kernel(const float* __restrict__ x,
                                                    __bf16* __restrict__ xb) {
  const size_t i = (size_t)blockIdx.x * 256 + threadIdx.x;   // 8-elem chunk id
  const size_t row = i >> 6;
  const int c = (int)(i & 63) * 8;
  if (row >= MP) return;
  bf16x8v o;
  if (row < N_NODES) {
    const float* p = x + row * 512 + c;
    f32x4 a = *(const f32x4*)p;
    f32x4 b = *(const f32x4*)(p + 4);
    o[0]=(__bf16)a[0]; o[1]=(__bf16)a[1]; o[2]=(__bf16)a[2]; o[3]=(__bf16)a[3];
    o[4]=(__bf16)b[0]; o[5]=(__bf16)b[1]; o[6]=(__bf16)b[2]; o[7]=(__bf16)b[3];
  } else {
    for (int j = 0; j < 8; ++j) o[j] = (__bf16)0.0f;
  }
  *(bf16x8v*)(xb + row * 512 + c) = o;
}

// ---------------- weight transpose: W[K][N] fp32 -> BT[N][K] bf16 ----------------
__global__ __launch_bounds__(256) void transpose_kernel(const float* __restrict__ W,
                                                        __bf16* __restrict__ BT,
                                                        int K, int Nn) {
  __shared__ float tile[32][33];
  const int bx = blockIdx.x;   // n tile
  const int by = blockIdx.y;   // k tile
  const int tx = threadIdx.x & 31;
  const int ty = threadIdx.x >> 5;   // 0..7
  for (int j = 0; j < 4; ++j) {
    int k = by * 32 + ty + j * 8;
    int n = bx * 32 + tx;
    tile[ty + j * 8][tx] = W[(size_t)k * Nn + n];
  }
  __syncthreads();
  for (int j = 0; j < 4; ++j) {
    int n = bx * 32 + ty + j * 8;
    int k = by * 32 + tx;
    BT[(size_t)n * K + k] = (__bf16)tile[tx][ty + j * 8];
  }
}

// ---------------- CSR build ----------------
__global__ __launch_bounds__(256) void degree_kernel(const int* __restrict__ dst,
                                                     int* __restrict__ deg) {
  int e = blockIdx.x * 256 + threadIdx.x;
  if (e < N_EDGES) atomicAdd(&deg[dst[e]], 1);
}

__global__ __launch_bounds__(256) void scan1_kernel(const int* __restrict__ deg,
                                                    int* __restrict__ rs,
                                                    int* __restrict__ bsum, int n) {
  __shared__ int lds[256];
  const int b = blockIdx.x, t = threadIdx.x;
  const int base = b * 1024 + t * 4;
  int v[4];
  for (int j = 0; j < 4; ++j) v[j] = (base + j < n) ? deg[base + j] : 0;
  int tsum = v[0] + v[1] + v[2] + v[3];
  lds[t] = tsum;
  __syncthreads();
  for (int off = 1; off < 256; off <<= 1) {
    int x = 0;
    if (t >= off) x = lds[t - off];
    __syncthreads();
    lds[t] += x;
    __syncthreads();
  }
  int run = lds[t] - tsum;   // exclusive prefix of this thread
  for (int j = 0; j < 4; ++j) {
    if (base + j < n) rs[base + j] = run;
    run += v[j];
  }
  if (t == 255) bsum[b] = lds[255];
}

__global__ void scan2_kernel(int* bsum, int nb) {
  if (threadIdx.x == 0 && blockIdx.x == 0) {
    int run = 0;
    for (int i = 0; i < nb; ++i) { int v = bsum[i]; bsum[i] = run; run += v; }
  }
}

__global__ __launch_bounds__(256) void scan3_kernel(int* __restrict__ rs,
                                                    const int* __restrict__ bsum,
                                                    int* __restrict__ cursor, int n) {
  int i = blockIdx.x * 256 + threadIdx.x;
  if (i < n) {
    int v = rs[i] + bsum[i >> 10];
    rs[i] = v;
    cursor[i] = v;
  } else if (i == n) {
    rs[n] = N_EDGES;
  }
}

__global__ __launch_bounds__(256) void scatter_kernel(const int* __restrict__ src,
                                                      const int* __restrict__ dst,
                                                      int* __restrict__ cursor,
                                                      int* __restrict__ csr) {
  int e = blockIdx.x * 256 + threadIdx.x;
  if (e < N_EDGES) {
    int slot = atomicAdd(&cursor[dst[e]], 1);
    csr[slot] = src[e];
  }
}

// ---------------- aggregate: agg[n] = sum_{e: dst==n} h[src[e]]  (pull, CSR) ----------------
__global__ __launch_bounds__(256) void aggregate_kernel(const __bf16* __restrict__ h,
                                                        const int* __restrict__ rs,
                                                        const int* __restrict__ csr,
                                                        __bf16* __restrict__ agg) {
  const int node = blockIdx.x * 4 + (threadIdx.x >> 6);
  if (node >= N_NODES) return;
  const int lane = threadIdx.x & 63;
  const int s = rs[node], e = rs[node + 1];
  float acc[8] = {0.f,0.f,0.f,0.f,0.f,0.f,0.f,0.f};
  for (int i = s; i < e; ++i) {
    int sn = csr[i];
    bf16x8v v = *(const bf16x8v*)(h + (size_t)sn * 512 + lane * 8);
    for (int j = 0; j < 8; ++j) acc[j] += (float)v[j];
  }
  bf16x8v o;
  for (int j = 0; j < 8; ++j) o[j] = (__bf16)acc[j];
  *(bf16x8v*)(agg + (size_t)node * 512 + lane * 8) = o;
}

// ---------------- GEMM: C[M][512] = relu?( A @ BT^T + bias ), bf16 in/out, fp32 acc ----------
template<int KTOT, bool SPLIT, bool RELU>
__global__ __launch_bounds__(256) void gemm_kernel(const __bf16* __restrict__ A1,
                                                   const __bf16* __restrict__ A2,
                                                   const __bf16* __restrict__ BT,
                                                   const float* __restrict__ bias,
                                                   __bf16* __restrict__ C) {
  __shared__ __bf16 As[128 * 32];
  __shared__ __bf16 Bs[128 * 32];
  const int tid  = threadIdx.x;
  const int wid  = tid >> 6;
  const int lane = tid & 63;
  const int tm = blockIdx.y, tn = blockIdx.x;
  const int wm = wid >> 1, wn = wid & 1;
  const int srow = tid >> 2;          // 0..63
  const int scol = (tid & 3) * 8;     // 0,8,16,24

  f32x4 acc[4][4];
  for (int m = 0; m < 4; ++m)
    for (int n = 0; n < 4; ++n)
      acc[m][n] = f32x4{0.f, 0.f, 0.f, 0.f};

  const int KA = SPLIT ? (KTOT / 2) : KTOT;

  for (int kt = 0; kt < KTOT; kt += 32) {
    const __bf16* Ap = A1;
    int kc = kt;
    if (SPLIT && kt >= KA) { Ap = A2; kc = kt - KA; }
    for (int j = 0; j < 2; ++j) {
      const __bf16* g = Ap + (size_t)(tm * 128 + j * 64 + srow) * KA + (kc + scol);
      gload_lds16(g, (char*)As + j * 4096 + wid * 1024);
    }
    for (int j = 0; j < 2; ++j) {
      const __bf16* g = BT + (size_t)(tn * 128 + j * 64 + srow) * KTOT + (kt + scol);
      gload_lds16(g, (char*)Bs + j * 4096 + wid * 1024);
    }
    __syncthreads();

    const int k8 = (lane >> 4) * 8;
    const int rl = lane & 15;
    bf16x8v av[4], bv[4];
    for (int m = 0; m < 4; ++m)
      av[m] = *(const bf16x8v*)(As + (wm * 64 + m * 16 + rl) * 32 + k8);
    for (int n = 0; n < 4; ++n)
      bv[n] = *(const bf16x8v*)(Bs + (wn * 64 + n * 16 + rl) * 32 + k8);
    for (int m = 0; m < 4; ++m)
      for (int n = 0; n < 4; ++n)
        acc[m][n] = __builtin_amdgcn_mfma_f32_16x16x32_bf16(av[m], bv[n], acc[m][n], 0, 0, 0);
    __syncthreads();
  }

  const int rl = lane & 15;
  const int rg = (lane >> 4) * 4;
  for (int n = 0; n < 4; ++n) {
    const int col = tn * 128 + wn * 64 + n * 16 + rl;
    const float bv_ = bias[col];
    for (int m = 0; m < 4; ++m) {
      const int rowb = tm * 128 + wm * 64 + m * 16 + rg;
      for (int r = 0; r < 4; ++r) {
        float v = acc[m][n][r] + bv_;
        if (RELU) v = fmaxf(v, 0.f);
        C[(size_t)(rowb + r) * NH + col] = (__bf16)v;
      }
    }
  }
}

// ---------------- memory module: h = softmax(h @ mem^T) @ mem ; also write hc slice --------
__global__ __launch_bounds__(256) void memmod_kernel(__bf16* __restrict__ h,
                                                     const float* __restrict__ mem,
                                                     __bf16* __restrict__ hc, int colofs) {
  __shared__ float sm[8 * 512];
  const int tid = threadIdx.x;
  for (int i = tid; i < 4096; i += 256) sm[i] = mem[i];
  __syncthreads();
  const int node = blockIdx.x * 4 + (tid >> 6);
  if (node >= N_NODES) return;
  const int lane = tid & 63;
  __bf16* hrow = h + (size_t)node * 512;
  float hv[8];
  for (int j = 0; j < 8; ++j) hv[j] = (float)hrow[lane + j * 64];
  float sim[8];
  for (int m = 0; m < 8; ++m) {
    float p = 0.f;
    const float* mr = sm + m * 512 + lane;
    for (int j = 0; j < 8; ++j) p += hv[j] * mr[j * 64];
    for (int off = 32; off; off >>= 1) p += __shfl_xor(p, off, 64);
    sim[m] = p;
  }
  float mx = sim[0];
  for (int m = 1; m < 8; ++m) mx = fmaxf(mx, sim[m]);
  float s = 0.f;
  for (int m = 0; m < 8; ++m) { sim[m] = __expf(sim[m] - mx); s += sim[m]; }
  const float inv = 1.f / s;
  float outv[8] = {0.f,0.f,0.f,0.f,0.f,0.f,0.f,0.f};
  for (int m = 0; m < 8; ++m) {
    float w = sim[m] * inv;
    const float* mr = sm + m * 512 + lane;
    for (int j = 0; j < 8; ++j) outv[j] += w * mr[j * 64];
  }
  __bf16* hcrow = hc + (size_t)node * 1024 + colofs;
  for (int j = 0; j < 8; ++j) {
    __bf16 o = (__bf16)outv[j];
    hrow[lane + j * 64] = o;
    hcrow[lane + j * 64] = o;
  }
}

// ---------------- graph ranges (batch is sorted) ----------------
__global__ __launch_bounds__(256) void ranges_kernel(const int* __restrict__ batch,
                                                     int* __restrict__ gstart) {
  int g = blockIdx.x * 256 + threadIdx.x;
  if (g > N_GRAPH) return;
  if (g == N_GRAPH) { gstart[N_GRAPH] = N_NODES; return; }
  int lo = 0, hi = N_NODES;
  while (lo < hi) {
    int mid = (lo + hi) >> 1;
    if (batch[mid] < g) lo = mid + 1; else hi = mid;
  }
  gstart[g] = lo;
}

// ---------------- pooling phase 1: segmented max/sum over hc [N][1024] ----------------
// 128 rows per block; 256 threads x 4 feats = full 1024-wide row. Flush atomics only at
// graph boundaries (batch sorted -> ~1.3 flushes per block).
__global__ __launch_bounds__(256) void pool1_kernel(const __bf16* __restrict__ hc,
                                                    const int* __restrict__ batch,
                                                    unsigned* __restrict__ gmax,
                                                    float* __restrict__ gsum) {
  __shared__ int bsh[128];
  const int r0 = blockIdx.x * 128;
  const int t = threadIdx.x;
  const int nrows = min(128, N_NODES - r0);
  if (t < nrows) bsh[t] = batch[r0 + t];
  __syncthreads();
  float mx[4] = {-3.0e38f, -3.0e38f, -3.0e38f, -3.0e38f};
  float sm[4] = {0.f, 0.f, 0.f, 0.f};
  int cur = -1;
  for (int r = 0; r < nrows; ++r) {
    int g = bsh[r];
    if (g != cur) {
      if (cur >= 0) {
#pragma unroll
        for (int j = 0; j < 4; ++j) {
          atomicMax(&gmax[(size_t)cur * 1024 + t * 4 + j], enc_f32(mx[j]));
          atomicAdd(&gsum[(size_t)cur * 1024 + t * 4 + j], sm[j]);
        }
      }
      cur = g;
#pragma unroll
      for (int j = 0; j < 4; ++j) { mx[j] = -3.0e38f; sm[j] = 0.f; }
    }
    bf16x4v v = *(const bf16x4v*)(hc + (size_t)(r0 + r) * 1024 + t * 4);
#pragma unroll
    for (int j = 0; j < 4; ++j) {
      float f = (float)v[j];
      mx[j] = fmaxf(mx[j], f);
      sm[j] += f;
    }
  }
  if (cur >= 0) {
#pragma unroll
    for (int j = 0; j < 4; ++j) {
      atomicMax(&gmax[(size_t)cur * 1024 + t * 4 + j], enc_f32(mx[j]));
      atomicAdd(&gsum[(size_t)cur * 1024 + t * 4 + j], sm[j]);
    }
  }
}

// ---------------- pooling phase 2: decode to gf [G][2048] = [max | mean] ----------------
__global__ __launch_bounds__(256) void pool2_kernel(const unsigned* __restrict__ gmax,
                                                    const float* __restrict__ gsum,
                                                    const int* __restrict__ gstart,
                                                    float* __restrict__ g) {
  const int gr = blockIdx.x;
  const int t = threadIdx.x;
  const int cnt = gstart[gr + 1] - gstart[gr];
  const float inv = 1.f / fmaxf((float)cnt, 1.f);
#pragma unroll
  for (int j = 0; j < 4; ++j) {
    const int f = t * 4 + j;
    unsigned u = gmax[(size_t)gr * 1024 + f];
    g[(size_t)gr * 2048 + f] = (cnt > 0) ? dec_f32(u) : 0.f;
    g[(size_t)gr * 2048 + 1024 + f] = gsum[(size_t)gr * 1024 + f] * inv;
  }
}

// ---------------- classifier head: log_softmax(g @ lin_w + lin_b) ----------------
__global__ __launch_bounds__(64) void classify_kernel(const float* __restrict__ g,
                                                      const float* __restrict__ lw,
                                                      const float* __restrict__ lb,
                                                      float* __restrict__ out) {
  const int gr = blockIdx.x;
  const int lane = threadIdx.x;   // 64
  float acc[10];
  for (int c = 0; c < 10; ++c) acc[c] = 0.f;
  const float* grow = g + (size_t)gr * 2048;
  for (int k = lane; k < 2048; k += 64) {
    float gv = grow[k];
    const float* w = lw + (size_t)k * 10;
#pragma unroll
    for (int c = 0; c < 10; ++c) acc[c] += gv * w[c];
  }
  for (int c = 0; c < 10; ++c)
    for (int off = 32; off; off >>= 1) acc[c] += __shfl_xor(acc[c], off, 64);
  if (lane == 0) {
    float lg[10];
    float mx = -3.0e38f;
    for (int c = 0; c < 10; ++c) { lg[c] = acc[c] + lb[c]; mx = fmaxf(mx, lg[c]); }
    float s = 0.f;
    for (int c = 0; c < 10; ++c) s += expf(lg[c] - mx);
    float lse = logf(s);
    for (int c = 0; c < 10; ++c) out[(size_t)gr * 10 + c] = lg[c] - mx - lse;
  }
}

// =======================================================================================
extern "C" void kernel_launch(void* const* d_in, const int* in_sizes, int n_in,
                              void* d_out, int out_size, void* d_ws, size_t ws_size,
                              hipStream_t stream) {
  (void)in_sizes; (void)n_in; (void)out_size; (void)ws_size;
  const float* x      = (const float*)d_in[0];
  const int*   eidx   = (const int*)d_in[1];
  const int*   batch  = (const int*)d_in[2];
  const float* pre_w  = (const float*)d_in[4];
  const float* pre_b  = (const float*)d_in[5];
  const float* w1_0   = (const float*)d_in[6];
  const float* b1_0   = (const float*)d_in[7];
  const float* w2_0   = (const float*)d_in[8];
  const float* b2_0   = (const float*)d_in[9];
  const float* mem_0  = (const float*)d_in[10];
  const float* w1_1   = (const float*)d_in[11];
  const float* b1_1   = (const float*)d_in[12];
  const float* w2_1   = (const float*)d_in[13];
  const float* b2_1   = (const float*)d_in[14];
  const float* mem_1  = (const float*)d_in[15];
  const float* lin_w  = (const float*)d_in[16];
  const float* lin_b  = (const float*)d_in[17];
  float* out = (float*)d_out;

  const int* src = eidx;
  const int* dst = eidx + N_EDGES;

  // ---- workspace carve ----
  char* p = (char*)d_ws;
  auto alloc = [&](size_t bytes) -> char* {
    char* r = p;
    p += (bytes + 255) & ~(size_t)255;
    return r;
  };
  __bf16* xb    = (__bf16*)alloc((size_t)MP * 512 * 2);
  __bf16* hb    = (__bf16*)alloc((size_t)MP * 512 * 2);
  __bf16* aggb  = (__bf16*)alloc((size_t)MP * 512 * 2);
  __bf16* y1b   = (__bf16*)alloc((size_t)MP * 512 * 2);
  __bf16* hcb   = (__bf16*)alloc((size_t)MP * 1024 * 2);
  __bf16* preT  = (__bf16*)alloc((size_t)512 * 512 * 2);
  __bf16* w1T0  = (__bf16*)alloc((size_t)512 * 1024 * 2);
  __bf16* w2T0  = (__bf16*)alloc((size_t)512 * 512 * 2);
  __bf16* w1T1  = (__bf16*)alloc((size_t)512 * 1024 * 2);
  __bf16* w2T1  = (__bf16*)alloc((size_t)512 * 512 * 2);
  int* deg      = (int*)alloc((size_t)N_NODES * 4);
  int* rowstart = (int*)alloc((size_t)(N_NODES + 1) * 4);
  int* cursor   = (int*)alloc((size_t)N_NODES * 4);
  int* bsum     = (int*)alloc(128 * 4);
  int* csr      = (int*)alloc((size_t)N_EDGES * 4);
  int* gstart   = (int*)alloc((size_t)(N_GRAPH + 1) * 4);
  float* gf     = (float*)alloc((size_t)N_GRAPH * 2048 * 4);
  unsigned* gmax = (unsigned*)alloc((size_t)N_GRAPH * 1024 * 4);
  float* gsum    = (float*)alloc((size_t)N_GRAPH * 1024 * 4);

  // ---- weight prep (bf16 transposed: BT[n][k]) ----
  transpose_kernel<<<dim3(16, 16), 256, 0, stream>>>(pre_w, preT, 512, 512);
  transpose_kernel<<<dim3(16, 32), 256, 0, stream>>>(w1_0, w1T0, 1024, 512);
  transpose_kernel<<<dim3(16, 16), 256, 0, stream>>>(w2_0, w2T0, 512, 512);
  transpose_kernel<<<dim3(16, 32), 256, 0, stream>>>(w1_1, w1T1, 1024, 512);
  transpose_kernel<<<dim3(16, 16), 256, 0, stream>>>(w2_1, w2T1, 512, 512);

  // ---- input cast ----
  castx_kernel<<<25024, 256, 0, stream>>>(x, xb);

  // ---- CSR build (per call; deterministic work) ----
  hipMemsetAsync(deg, 0, (size_t)N_NODES * 4, stream);
  degree_kernel<<<3125, 256, 0, stream>>>(dst, deg);
  scan1_kernel<<<98, 256, 0, stream>>>(deg, rowstart, bsum, N_NODES);
  scan2_kernel<<<1, 64, 0, stream>>>(bsum, 98);
  scan3_kernel<<<392, 256, 0, stream>>>(rowstart, bsum, cursor, N_NODES);
  scatter_kernel<<<3125, 256, 0, stream>>>(src, dst, cursor, csr);

  // pooling accumulators: gmax||gsum are contiguous -> one memset
  hipMemsetAsync(gmax, 0, (size_t)N_GRAPH * 1024 * 4 * 2, stream);
  ranges_kernel<<<2, 256, 0, stream>>>(batch, gstart);

  const dim3 ggrid(4, 782);

  // ---- pre conv: h = x @ pre_w + pre_b ----
  gemm_kernel<512, false, false><<<ggrid, 256, 0, stream>>>(xb, nullptr, preT, pre_b, hb);

  // ---- layer 0 ----
  aggregate_kernel<<<25000, 256, 0, stream>>>(hb, rowstart, csr, aggb);
  gemm_kernel<1024, true, true><<<ggrid, 256, 0, stream>>>(hb, aggb, w1T0, b1_0, y1b);
  gemm_kernel<512, false, true><<<ggrid, 256, 0, stream>>>(y1b, nullptr, w2T0, b2_0, hb);
  memmod_kernel<<<25000, 256, 0, stream>>>(hb, mem_0, hcb, 0);

  // ---- layer 1 ----
  aggregate_kernel<<<25000, 256, 0, stream>>>(hb, rowstart, csr, aggb);
  gemm_kernel<1024, true, true><<<ggrid, 256, 0, stream>>>(hb, aggb, w1T1, b1_1, y1b);
  gemm_kernel<512, false, true><<<ggrid, 256, 0, stream>>>(y1b, nullptr, w2T1, b2_1, hb);
  memmod_kernel<<<25000, 256, 0, stream>>>(hb, mem_1, hcb, 512);

  // ---- readout ----
  pool1_kernel<<<782, 256, 0, stream>>>(hcb, batch, gmax, gsum);
  pool2_kernel<<<N_GRAPH, 256, 0, stream>>>(gmax, gsum, gstart, gf);
  classify_kernel<<<N_GRAPH, 64, 0, stream>>>(gf, lin_w, lin_b, out);
}

// Round 3
// 1263.794 us; speedup vs baseline: 1.1154x; 1.0359x over previous
//
#include <hip/hip_runtime.h>

#define N_NODES 100000
#define N_EDGES 800000
#define N_GRAPH 256
#define MP      100096   // 782 * 128, padded M
#define NH      512

typedef __bf16 bf16x4v __attribute__((ext_vector_type(4)));
typedef __bf16 bf16x8v __attribute__((ext_vector_type(8)));
typedef float  f32x4   __attribute__((ext_vector_type(4)));

__device__ __forceinline__ void gload_lds16(const void* g, void* l) {
  __builtin_amdgcn_global_load_lds((const __attribute__((address_space(1))) void*)g,
                                   (__attribute__((address_space(3))) void*)l, 16, 0, 0);
}

// order-preserving fp32 <-> uint32 encoding for atomicMax
__device__ __forceinline__ unsigned enc_f32(float f) {
  unsigned u = __float_as_uint(f);
  return (u & 0x80000000u) ? ~u : (u | 0x80000000u);
}
__device__ __forceinline__ float dec_f32(unsigned u) {
  return (u & 0x80000000u) ? __uint_as_float(u & 0x7FFFFFFFu) : __uint_as_float(~u);
}

// ---------------- cast x (fp32) -> padded bf16 [MP][512] ----------------
__global__ __launch_bounds__(256) void castx_kernel(const float* __restrict__ x,
                                                    __bf16* __restrict__ xb) {
  const size_t i = (size_t)blockIdx.x * 256 + threadIdx.x;   // 8-elem chunk id
  const size_t row = i >> 6;
  const int c = (int)(i & 63) * 8;
  if (row >= MP) return;
  bf16x8v o;
  if (row < N_NODES) {
    const float* p = x + row * 512 + c;
    f32x4 a = *(const f32x4*)p;
    f32x4 b = *(const f32x4*)(p + 4);
    o[0]=(__bf16)a[0]; o[1]=(__bf16)a[1]; o[2]=(__bf16)a[2]; o[3]=(__bf16)a[3];
    o[4]=(__bf16)b[0]; o[5]=(__bf16)b[1]; o[6]=(__bf16)b[2]; o[7]=(__bf16)b[3];
  } else {
    for (int j = 0; j < 8; ++j) o[j] = (__bf16)0.0f;
  }
  *(bf16x8v*)(xb + row * 512 + c) = o;
}

// ---------------- weight transpose: W[K][N] fp32 -> BT[N][K] bf16 ----------------
__global__ __launch_bounds__(256) void transpose_kernel(const float* __restrict__ W,
                                                        __bf16* __restrict__ BT,
                                                        int K, int Nn) {
  __shared__ float tile[32][33];
  const int bx = blockIdx.x;   // n tile
  const int by = blockIdx.y;   // k tile
  const int tx = threadIdx.x & 31;
  const int ty = threadIdx.x >> 5;   // 0..7
  for (int j = 0; j < 4; ++j) {
    int k = by * 32 + ty + j * 8;
    int n = bx * 32 + tx;
    tile[ty + j * 8][tx] = W[(size_t)k * Nn + n];
  }
  __syncthreads();
  for (int j = 0; j < 4; ++j) {
    int n = bx * 32 + ty + j * 8;
    int k = by * 32 + tx;
    BT[(size_t)n * K + k] = (__bf16)tile[tx][ty + j * 8];
  }
}

// ---------------- CSR build ----------------
__global__ __launch_bounds__(256) void degree_kernel(const int* __restrict__ dst,
                                                     int* __restrict__ deg) {
  int e = blockIdx.x * 256 + threadIdx.x;
  if (e < N_EDGES) atomicAdd(&deg[dst[e]], 1);
}

__global__ __launch_bounds__(256) void scan1_kernel(const int* __restrict__ deg,
                                                    int* __restrict__ rs,
                                                    int* __restrict__ bsum, int n) {
  __shared__ int lds[256];
  const int b = blockIdx.x, t = threadIdx.x;
  const int base = b * 1024 + t * 4;
  int v[4];
  for (int j = 0; j < 4; ++j) v[j] = (base + j < n) ? deg[base + j] : 0;
  int tsum = v[0] + v[1] + v[2] + v[3];
  lds[t] = tsum;
  __syncthreads();
  for (int off = 1; off < 256; off <<= 1) {
    int x = 0;
    if (t >= off) x = lds[t - off];
    __syncthreads();
    lds[t] += x;
    __syncthreads();
  }
  int run = lds[t] - tsum;   // exclusive prefix of this thread
  for (int j = 0; j < 4; ++j) {
    if (base + j < n) rs[base + j] = run;
    run += v[j];
  }
  if (t == 255) bsum[b] = lds[255];
}

__global__ void scan2_kernel(int* bsum, int nb) {
  if (threadIdx.x == 0 && blockIdx.x == 0) {
    int run = 0;
    for (int i = 0; i < nb; ++i) { int v = bsum[i]; bsum[i] = run; run += v; }
  }
}

__global__ __launch_bounds__(256) void scan3_kernel(int* __restrict__ rs,
                                                    const int* __restrict__ bsum,
                                                    int* __restrict__ cursor, int n) {
  int i = blockIdx.x * 256 + threadIdx.x;
  if (i < n) {
    int v = rs[i] + bsum[i >> 10];
    rs[i] = v;
    cursor[i] = v;
  } else if (i == n) {
    rs[n] = N_EDGES;
  }
}

__global__ __launch_bounds__(256) void scatter_kernel(const int* __restrict__ src,
                                                      const int* __restrict__ dst,
                                                      int* __restrict__ cursor,
                                                      int* __restrict__ csr) {
  int e = blockIdx.x * 256 + threadIdx.x;
  if (e < N_EDGES) {
    int slot = atomicAdd(&cursor[dst[e]], 1);
    csr[slot] = src[e];
  }
}

// ---------------- aggregate: agg[n] = sum_{e: dst==n} h[src[e]]  (pull, CSR) ----------------
__global__ __launch_bounds__(256) void aggregate_kernel(const __bf16* __restrict__ h,
                                                        const int* __restrict__ rs,
                                                        const int* __restrict__ csr,
                                                        __bf16* __restrict__ agg) {
  const int node = blockIdx.x * 4 + (threadIdx.x >> 6);
  if (node >= N_NODES) return;
  const int lane = threadIdx.x & 63;
  const int s = rs[node], e = rs[node + 1];
  float acc[8] = {0.f,0.f,0.f,0.f,0.f,0.f,0.f,0.f};
  for (int i = s; i < e; ++i) {
    int sn = csr[i];
    bf16x8v v = *(const bf16x8v*)(h + (size_t)sn * 512 + lane * 8);
    for (int j = 0; j < 8; ++j) acc[j] += (float)v[j];
  }
  bf16x8v o;
  for (int j = 0; j < 8; ++j) o[j] = (__bf16)acc[j];
  *(bf16x8v*)(agg + (size_t)node * 512 + lane * 8) = o;
}

// ---------------- GEMM: C[M][512] = relu?( A @ BT^T + bias ), bf16 in/out, fp32 acc ----------
// XCD-swizzled flat grid (3128 = 8 XCD * 391). LDS chunk-swizzle: 16B chunk index XOR'd
// with (row>>1)&3 (involution; inverse-swizzled global source + swizzled ds_read, LDS
// dest stays linear for global_load_lds).
template<int KTOT, bool SPLIT, bool RELU>
__global__ __launch_bounds__(256) void gemm_kernel(const __bf16* __restrict__ A1,
                                                   const __bf16* __restrict__ A2,
                                                   const __bf16* __restrict__ BT,
                                                   const float* __restrict__ bias,
                                                   __bf16* __restrict__ C) {
  __shared__ __bf16 As[128 * 32];
  __shared__ __bf16 Bs[128 * 32];
  const int tid  = threadIdx.x;
  const int wid  = tid >> 6;
  const int lane = tid & 63;
  // XCD-aware bijective remap: all 4 N-tiles of a given tm land on the same XCD
  const int idx = (blockIdx.x & 7) * 391 + (blockIdx.x >> 3);
  const int tm = idx >> 2, tn = idx & 3;
  const int wm = wid >> 1, wn = wid & 1;
  const int srow = tid >> 2;                         // 0..63 (row within 64-row half)
  const int scol = (((tid & 3) ^ ((tid >> 3) & 3)) * 8);  // inverse-swizzled source chunk

  f32x4 acc[4][4];
  for (int m = 0; m < 4; ++m)
    for (int n = 0; n < 4; ++n)
      acc[m][n] = f32x4{0.f, 0.f, 0.f, 0.f};

  const int KA = SPLIT ? (KTOT / 2) : KTOT;
  // swizzled read chunk: (lane>>4) ^ ((row>>1)&3); row offsets are 0 mod 4 so it
  // reduces to lane bits only
  const int rdk = (((lane >> 4) ^ ((lane >> 1) & 3)) * 8);
  const int rl = lane & 15;

  for (int kt = 0; kt < KTOT; kt += 32) {
    const __bf16* Ap = A1;
    int kc = kt;
    if (SPLIT && kt >= KA) { Ap = A2; kc = kt - KA; }
    for (int j = 0; j < 2; ++j) {
      const __bf16* g = Ap + (size_t)(tm * 128 + j * 64 + srow) * KA + (kc + scol);
      gload_lds16(g, (char*)As + j * 4096 + wid * 1024);
    }
    for (int j = 0; j < 2; ++j) {
      const __bf16* g = BT + (size_t)(tn * 128 + j * 64 + srow) * KTOT + (kt + scol);
      gload_lds16(g, (char*)Bs + j * 4096 + wid * 1024);
    }
    __syncthreads();

    bf16x8v av[4], bv[4];
    for (int m = 0; m < 4; ++m)
      av[m] = *(const bf16x8v*)(As + (wm * 64 + m * 16 + rl) * 32 + rdk);
    for (int n = 0; n < 4; ++n)
      bv[n] = *(const bf16x8v*)(Bs + (wn * 64 + n * 16 + rl) * 32 + rdk);
    for (int m = 0; m < 4; ++m)
      for (int n = 0; n < 4; ++n)
        acc[m][n] = __builtin_amdgcn_mfma_f32_16x16x32_bf16(av[m], bv[n], acc[m][n], 0, 0, 0);
    __syncthreads();
  }

  const int rg = (lane >> 4) * 4;
  for (int n = 0; n < 4; ++n) {
    const int col = tn * 128 + wn * 64 + n * 16 + rl;
    const float bv_ = bias[col];
    for (int m = 0; m < 4; ++m) {
      const int rowb = tm * 128 + wm * 64 + m * 16 + rg;
      for (int r = 0; r < 4; ++r) {
        float v = acc[m][n][r] + bv_;
        if (RELU) v = fmaxf(v, 0.f);
        C[(size_t)(rowb + r) * NH + col] = (__bf16)v;
      }
    }
  }
}

// ---------------- memory module: h = softmax(h @ mem^T) @ mem ; also write hc slice --------
__global__ __launch_bounds__(256) void memmod_kernel(__bf16* __restrict__ h,
                                                     const float* __restrict__ mem,
                                                     __bf16* __restrict__ hc, int colofs) {
  __shared__ float sm[8 * 512];
  const int tid = threadIdx.x;
  for (int i = tid; i < 4096; i += 256) sm[i] = mem[i];
  __syncthreads();
  const int node = blockIdx.x * 4 + (tid >> 6);
  if (node >= N_NODES) return;
  const int lane = tid & 63;
  __bf16* hrow = h + (size_t)node * 512;
  float hv[8];
  for (int j = 0; j < 8; ++j) hv[j] = (float)hrow[lane + j * 64];
  float sim[8];
  for (int m = 0; m < 8; ++m) {
    float p = 0.f;
    const float* mr = sm + m * 512 + lane;
    for (int j = 0; j < 8; ++j) p += hv[j] * mr[j * 64];
    for (int off = 32; off; off >>= 1) p += __shfl_xor(p, off, 64);
    sim[m] = p;
  }
  float mx = sim[0];
  for (int m = 1; m < 8; ++m) mx = fmaxf(mx, sim[m]);
  float s = 0.f;
  for (int m = 0; m < 8; ++m) { sim[m] = __expf(sim[m] - mx); s += sim[m]; }
  const float inv = 1.f / s;
  float outv[8] = {0.f,0.f,0.f,0.f,0.f,0.f,0.f,0.f};
  for (int m = 0; m < 8; ++m) {
    float w = sim[m] * inv;
    const float* mr = sm + m * 512 + lane;
    for (int j = 0; j < 8; ++j) outv[j] += w * mr[j * 64];
  }
  __bf16* hcrow = hc + (size_t)node * 1024 + colofs;
  for (int j = 0; j < 8; ++j) {
    __bf16 o = (__bf16)outv[j];
    hrow[lane + j * 64] = o;
    hcrow[lane + j * 64] = o;
  }
}

// ---------------- graph ranges (batch is sorted) ----------------
__global__ __launch_bounds__(256) void ranges_kernel(const int* __restrict__ batch,
                                                     int* __restrict__ gstart) {
  int g = blockIdx.x * 256 + threadIdx.x;
  if (g > N_GRAPH) return;
  if (g == N_GRAPH) { gstart[N_GRAPH] = N_NODES; return; }
  int lo = 0, hi = N_NODES;
  while (lo < hi) {
    int mid = (lo + hi) >> 1;
    if (batch[mid] < g) lo = mid + 1; else hi = mid;
  }
  gstart[g] = lo;
}

// ---------------- pooling phase 1: segmented max/sum over hc [N][1024] ----------------
__global__ __launch_bounds__(256) void pool1_kernel(const __bf16* __restrict__ hc,
                                                    const int* __restrict__ batch,
                                                    unsigned* __restrict__ gmax,
                                                    float* __restrict__ gsum) {
  __shared__ int bsh[128];
  const int r0 = blockIdx.x * 128;
  const int t = threadIdx.x;
  const int nrows = min(128, N_NODES - r0);
  if (t < nrows) bsh[t] = batch[r0 + t];
  __syncthreads();
  float mx[4] = {-3.0e38f, -3.0e38f, -3.0e38f, -3.0e38f};
  float sm[4] = {0.f, 0.f, 0.f, 0.f};
  int cur = -1;
  for (int r = 0; r < nrows; ++r) {
    int g = bsh[r];
    if (g != cur) {
      if (cur >= 0) {
#pragma unroll
        for (int j = 0; j < 4; ++j) {
          atomicMax(&gmax[(size_t)cur * 1024 + t * 4 + j], enc_f32(mx[j]));
          atomicAdd(&gsum[(size_t)cur * 1024 + t * 4 + j], sm[j]);
        }
      }
      cur = g;
#pragma unroll
      for (int j = 0; j < 4; ++j) { mx[j] = -3.0e38f; sm[j] = 0.f; }
    }
    bf16x4v v = *(const bf16x4v*)(hc + (size_t)(r0 + r) * 1024 + t * 4);
#pragma unroll
    for (int j = 0; j < 4; ++j) {
      float f = (float)v[j];
      mx[j] = fmaxf(mx[j], f);
      sm[j] += f;
    }
  }
  if (cur >= 0) {
#pragma unroll
    for (int j = 0; j < 4; ++j) {
      atomicMax(&gmax[(size_t)cur * 1024 + t * 4 + j], enc_f32(mx[j]));
      atomicAdd(&gsum[(size_t)cur * 1024 + t * 4 + j], sm[j]);
    }
  }
}

// ---------------- pooling phase 2: decode to gf [G][2048] = [max | mean] ----------------
__global__ __launch_bounds__(256) void pool2_kernel(const unsigned* __restrict__ gmax,
                                                    const float* __restrict__ gsum,
                                                    const int* __restrict__ gstart,
                                                    float* __restrict__ g) {
  const int gr = blockIdx.x;
  const int t = threadIdx.x;
  const int cnt = gstart[gr + 1] - gstart[gr];
  const float inv = 1.f / fmaxf((float)cnt, 1.f);
#pragma unroll
  for (int j = 0; j < 4; ++j) {
    const int f = t * 4 + j;
    unsigned u = gmax[(size_t)gr * 1024 + f];
    g[(size_t)gr * 2048 + f] = (cnt > 0) ? dec_f32(u) : 0.f;
    g[(size_t)gr * 2048 + 1024 + f] = gsum[(size_t)gr * 1024 + f] * inv;
  }
}

// ---------------- classifier head: log_softmax(g @ lin_w + lin_b) ----------------
__global__ __launch_bounds__(64) void classify_kernel(const float* __restrict__ g,
                                                      const float* __restrict__ lw,
                                                      const float* __restrict__ lb,
                                                      float* __restrict__ out) {
  const int gr = blockIdx.x;
  const int lane = threadIdx.x;   // 64
  float acc[10];
  for (int c = 0; c < 10; ++c) acc[c] = 0.f;
  const float* grow = g + (size_t)gr * 2048;
  for (int k = lane; k < 2048; k += 64) {
    float gv = grow[k];
    const float* w = lw + (size_t)k * 10;
#pragma unroll
    for (int c = 0; c < 10; ++c) acc[c] += gv * w[c];
  }
  for (int c = 0; c < 10; ++c)
    for (int off = 32; off; off >>= 1) acc[c] += __shfl_xor(acc[c], off, 64);
  if (lane == 0) {
    float lg[10];
    float mx = -3.0e38f;
    for (int c = 0; c < 10; ++c) { lg[c] = acc[c] + lb[c]; mx = fmaxf(mx, lg[c]); }
    float s = 0.f;
    for (int c = 0; c < 10; ++c) s += expf(lg[c] - mx);
    float lse = logf(s);
    for (int c = 0; c < 10; ++c) out[(size_t)gr * 10 + c] = lg[c] - mx - lse;
  }
}

// =======================================================================================
extern "C" void kernel_launch(void* const* d_in, const int* in_sizes, int n_in,
                              void* d_out, int out_size, void* d_ws, size_t ws_size,
                              hipStream_t stream) {
  (void)in_sizes; (void)n_in; (void)out_size; (void)ws_size;
  const float* x      = (const float*)d_in[0];
  const int*   eidx   = (const int*)d_in[1];
  const int*   batch  = (const int*)d_in[2];
  const float* pre_w  = (const float*)d_in[4];
  const float* pre_b  = (const float*)d_in[5];
  const float* w1_0   = (const float*)d_in[6];
  const float* b1_0   = (const float*)d_in[7];
  const float* w2_0   = (const float*)d_in[8];
  const float* b2_0   = (const float*)d_in[9];
  const float* mem_0  = (const float*)d_in[10];
  const float* w1_1   = (const float*)d_in[11];
  const float* b1_1   = (const float*)d_in[12];
  const float* w2_1   = (const float*)d_in[13];
  const float* b2_1   = (const float*)d_in[14];
  const float* mem_1  = (const float*)d_in[15];
  const float* lin_w  = (const float*)d_in[16];
  const float* lin_b  = (const float*)d_in[17];
  float* out = (float*)d_out;

  const int* src = eidx;
  const int* dst = eidx + N_EDGES;

  // ---- workspace carve ----
  char* p = (char*)d_ws;
  auto alloc = [&](size_t bytes) -> char* {
    char* r = p;
    p += (bytes + 255) & ~(size_t)255;
    return r;
  };
  __bf16* xb    = (__bf16*)alloc((size_t)MP * 512 * 2);
  __bf16* hb    = (__bf16*)alloc((size_t)MP * 512 * 2);
  __bf16* aggb  = (__bf16*)alloc((size_t)MP * 512 * 2);
  __bf16* y1b   = (__bf16*)alloc((size_t)MP * 512 * 2);
  __bf16* hcb   = (__bf16*)alloc((size_t)MP * 1024 * 2);
  __bf16* preT  = (__bf16*)alloc((size_t)512 * 512 * 2);
  __bf16* w1T0  = (__bf16*)alloc((size_t)512 * 1024 * 2);
  __bf16* w2T0  = (__bf16*)alloc((size_t)512 * 512 * 2);
  __bf16* w1T1  = (__bf16*)alloc((size_t)512 * 1024 * 2);
  __bf16* w2T1  = (__bf16*)alloc((size_t)512 * 512 * 2);
  int* deg      = (int*)alloc((size_t)N_NODES * 4);
  int* rowstart = (int*)alloc((size_t)(N_NODES + 1) * 4);
  int* cursor   = (int*)alloc((size_t)N_NODES * 4);
  int* bsum     = (int*)alloc(128 * 4);
  int* csr      = (int*)alloc((size_t)N_EDGES * 4);
  int* gstart   = (int*)alloc((size_t)(N_GRAPH + 1) * 4);
  float* gf     = (float*)alloc((size_t)N_GRAPH * 2048 * 4);
  unsigned* gmax = (unsigned*)alloc((size_t)N_GRAPH * 1024 * 4);
  float* gsum    = (float*)alloc((size_t)N_GRAPH * 1024 * 4);

  // ---- weight prep (bf16 transposed: BT[n][k]) ----
  transpose_kernel<<<dim3(16, 16), 256, 0, stream>>>(pre_w, preT, 512, 512);
  transpose_kernel<<<dim3(16, 32), 256, 0, stream>>>(w1_0, w1T0, 1024, 512);
  transpose_kernel<<<dim3(16, 16), 256, 0, stream>>>(w2_0, w2T0, 512, 512);
  transpose_kernel<<<dim3(16, 32), 256, 0, stream>>>(w1_1, w1T1, 1024, 512);
  transpose_kernel<<<dim3(16, 16), 256, 0, stream>>>(w2_1, w2T1, 512, 512);

  // ---- input cast ----
  castx_kernel<<<25024, 256, 0, stream>>>(x, xb);

  // ---- CSR build (per call; deterministic work) ----
  hipMemsetAsync(deg, 0, (size_t)N_NODES * 4, stream);
  degree_kernel<<<3125, 256, 0, stream>>>(dst, deg);
  scan1_kernel<<<98, 256, 0, stream>>>(deg, rowstart, bsum, N_NODES);
  scan2_kernel<<<1, 64, 0, stream>>>(bsum, 98);
  scan3_kernel<<<392, 256, 0, stream>>>(rowstart, bsum, cursor, N_NODES);
  scatter_kernel<<<3125, 256, 0, stream>>>(src, dst, cursor, csr);

  // pooling accumulators: gmax||gsum are contiguous -> one memset
  hipMemsetAsync(gmax, 0, (size_t)N_GRAPH * 1024 * 4 * 2, stream);
  ranges_kernel<<<2, 256, 0, stream>>>(batch, gstart);

  // ---- pre conv: h = x @ pre_w + pre_b ----
  gemm_kernel<512, false, false><<<3128, 256, 0, stream>>>(xb, nullptr, preT, pre_b, hb);

  // ---- layer 0 ----
  aggregate_kernel<<<25000, 256, 0, stream>>>(hb, rowstart, csr, aggb);
  gemm_kernel<1024, true, true><<<3128, 256, 0, stream>>>(hb, aggb, w1T0, b1_0, y1b);
  gemm_kernel<512, false, true><<<3128, 256, 0, stream>>>(y1b, nullptr, w2T0, b2_0, hb);
  memmod_kernel<<<25000, 256, 0, stream>>>(hb, mem_0, hcb, 0);

  // ---- layer 1 ----
  aggregate_kernel<<<25000, 256, 0, stream>>>(hb, rowstart, csr, aggb);
  gemm_kernel<1024, true, true><<<3128, 256, 0, stream>>>(hb, aggb, w1T1, b1_1, y1b);
  gemm_kernel<512, false, true><<<3128, 256, 0, stream>>>(y1b, nullptr, w2T1, b2_1, hb);
  memmod_kernel<<<25000, 256, 0, stream>>>(hb, mem_1, hcb, 512);

  // ---- readout ----
  pool1_kernel<<<782, 256, 0, stream>>>(hcb, batch, gmax, gsum);
  pool2_kernel<<<N_GRAPH, 256, 0, stream>>>(gmax, gsum, gstart, gf);
  classify_kernel<<<N_GRAPH, 64, 0, stream>>>(gf, lin_w, lin_b, out);
}